// Round 12
// baseline (175.362 us; speedup 1.0000x reference)
//
#include <hip/hip_runtime.h>
#include <hip/hip_bf16.h>
#include <cstddef>
#include <cstdint>

// Problem constants
#define B   32
#define C   16
#define H   64
#define D   256
#define K   2048
#define T   15
#define PAD 7
#define EPS 1e-5

#define BH      (B*H)       // 2048
#define ROWS    (B*C*H)     // 32768 VQ rows
#define N_PER_CH ((double)(B*H*D)) // 524288
#define NC  8               // candidates per row (global top-8)

typedef __attribute__((ext_vector_type(8))) short bf16x8;
typedef __attribute__((ext_vector_type(4))) float f32x4;

__device__ __forceinline__ void gload_lds16(const void* g, void* l) {
  __builtin_amdgcn_global_load_lds(
      (const __attribute__((address_space(1))) unsigned int*)g,
      (__attribute__((address_space(3))) unsigned int*)l, 16, 0, 0);
}

// ---------------------------------------------------------------------------
// K0 (fused): blocks [0,BH): stats-only encoder conv (f64) partial sums.
//             blocks [BH, BH+512): emb prep — enorm f64 (+f32) + bf16 cast.
// ---------------------------------------------------------------------------
__global__ __launch_bounds__(256) void k0_fused(
    const float* __restrict__ x, const float* __restrict__ w,
    double* __restrict__ partial /* [BH][C][2] */,
    const float* __restrict__ emb, double* __restrict__ enorm,
    float* __restrict__ enormf, __hip_bfloat16* __restrict__ embB) {
  __shared__ __attribute__((aligned(16))) float xs[272];
  __shared__ float wsm[C*T];
  const int bh = blockIdx.x, tid = threadIdx.x;
  if (bh >= BH) {
    const int k = (bh - BH) * 4 + (tid >> 6);
    const int lane = tid & 63;
    const float4 ev = *(const float4*)(emb + ((size_t)k << 8) + lane*4);
    __hip_bfloat16 hb[4] = {__float2bfloat16(ev.x), __float2bfloat16(ev.y),
                            __float2bfloat16(ev.z), __float2bfloat16(ev.w)};
    *(int2*)(embB + ((size_t)k << 8) + lane*4) = *(const int2*)hb;
    double s = fma((double)ev.x, (double)ev.x,
               fma((double)ev.y, (double)ev.y,
               fma((double)ev.z, (double)ev.z,
                   (double)ev.w * (double)ev.w)));
#pragma unroll
    for (int off = 1; off < 64; off <<= 1) s += __shfl_xor(s, off, 64);
    if (lane == 0) { enorm[k] = s; enormf[k] = (float)s; }
    return;
  }
  const float* xrow = x + ((size_t)bh << 8);
  if (tid < C*T) wsm[tid] = w[tid];
  xs[tid] = (tid >= 7 && tid < 263) ? xrow[tid - 7] : 0.f;
  if (tid < 16) { int i = 256 + tid; xs[i] = (i < 263) ? xrow[i - 7] : 0.f; }
  __syncthreads();
  const int c = tid >> 4, s = tid & 15;
  float xr[32];
#pragma unroll
  for (int kq = 0; kq < 8; kq++)
    *(float4*)&xr[kq*4] = *(const float4*)&xs[s*16 + kq*4];
  float wv[T];
#pragma unroll
  for (int t = 0; t < T; t++) wv[t] = wsm[c*T + t];
  double sum = 0.0, sq = 0.0;
#pragma unroll
  for (int d0 = 0; d0 < 16; d0++) {
    double z = 0.0;
#pragma unroll
    for (int t = 0; t < T; t++) z = fma((double)wv[t], (double)xr[d0 + t], z);
    sum += z; sq = fma(z, z, sq);
  }
#pragma unroll
  for (int off = 1; off < 16; off <<= 1) {
    sum += __shfl_xor(sum, off, 64);
    sq  += __shfl_xor(sq,  off, 64);
  }
  if (s == 0) {
    partial[(size_t)bh*(C*2) + c*2 + 0] = sum;
    partial[(size_t)bh*(C*2) + c*2 + 1] = sq;
  }
}

// ---------------------------------------------------------------------------
// K2: finalize BN per-channel params (deterministic tree)
// ---------------------------------------------------------------------------
__global__ __launch_bounds__(256) void k2_stats_final(
    const double* __restrict__ partial, const float* __restrict__ gamma,
    const float* __restrict__ beta, double* __restrict__ params) {
  __shared__ double rs[256], rq[256];
  const int c = blockIdx.x;
  const int tid = threadIdx.x;
  double s = 0.0, q = 0.0;
  for (int i = tid; i < BH; i += 256) {
    s += partial[(size_t)i * (C*2) + c*2 + 0];
    q += partial[(size_t)i * (C*2) + c*2 + 1];
  }
  rs[tid] = s; rq[tid] = q;
  __syncthreads();
  for (int off = 128; off; off >>= 1) {
    if (tid < off) { rs[tid] += rs[tid + off]; rq[tid] += rq[tid + off]; }
    __syncthreads();
  }
  if (tid == 0) {
    double m = rs[0] / N_PER_CH;
    double v = rq[0] / N_PER_CH - m * m;
    double a = (double)gamma[c] / sqrt(v + EPS);
    double b = (double)beta[c] - a * m;
    params[c*4+0] = m; params[c*4+1] = v; params[c*4+2] = a; params[c*4+3] = b;
  }
}

// ---------------------------------------------------------------------------
// K1b: encoder conv (f64) + fused affine -> z_e f32 (output) + z_e bf16 (k4 A)
// ---------------------------------------------------------------------------
__global__ __launch_bounds__(256) void k1b_ze(
    const float* __restrict__ x, const float* __restrict__ w,
    const double* __restrict__ params, float* __restrict__ zE,
    __hip_bfloat16* __restrict__ zEb) {
  __shared__ __attribute__((aligned(16))) float xs[272];
  __shared__ float wsm[C*T];
  const int bh = blockIdx.x, tid = threadIdx.x;
  const int b = bh >> 6, h = bh & 63;
  const float* xrow = x + ((size_t)bh << 8);
  if (tid < C*T) wsm[tid] = w[tid];
  xs[tid] = (tid >= 7 && tid < 263) ? xrow[tid - 7] : 0.f;
  if (tid < 16) { int i = 256 + tid; xs[i] = (i < 263) ? xrow[i - 7] : 0.f; }
  __syncthreads();
  const int c = tid >> 4, s = tid & 15;
  float xr[32];
#pragma unroll
  for (int kq = 0; kq < 8; kq++)
    *(float4*)&xr[kq*4] = *(const float4*)&xs[s*16 + kq*4];
  float wv[T];
#pragma unroll
  for (int t = 0; t < T; t++) wv[t] = wsm[c*T + t];
  const double a = params[c*4+2], bb = params[c*4+3];
  float zf[16];
  __hip_bfloat16 zb[16];
#pragma unroll
  for (int d0 = 0; d0 < 16; d0++) {
    double z = 0.0;
#pragma unroll
    for (int t = 0; t < T; t++) z = fma((double)wv[t], (double)xr[d0 + t], z);
    double ze = fma(a, z, bb);
    zf[d0] = (float)ze;
    zb[d0] = __float2bfloat16(zf[d0]);
  }
  const size_t rbase = ((((size_t)b*C + c)*H + h) << 8) + s*16;
#pragma unroll
  for (int kq = 0; kq < 4; kq++)
    *(float4*)(zE + rbase + kq*4) = *(const float4*)&zf[kq*4];
  *(int4*)(zEb + rbase)     = *(const int4*)&zb[0];
  *(int4*)(zEb + rbase + 8) = *(const int4*)&zb[8];
}

// ---------------------------------------------------------------------------
// K4: FAT-STEP MFMA phase-A. Block = 128 rows x full 2048 cols, 4 waves (2x2),
// 1 block/CU (LDS 136 KB), grid = 256 (exactly 1 round).
// A slab frag-order resident (64 KB). B 2-slot ring, slot = 128 cols x 128 k
// (32 KB): ONE synced step covers 4 inner sub-k iterations {8 ds_read_b128 +
// 16 MFMA} -> per-step sync tax amortized 4x vs BK=32. Counted vmcnt(8)
// (stage(t) issued a full step earlier). En pre-staged to LDS (no stray VMEM).
// Spread tracker epilogue (acc double-buffer, 8 vals per sub-k in MFMA shadow).
// ---------------------------------------------------------------------------
__global__ __launch_bounds__(256, 1) void k4_mfma(
    const __hip_bfloat16* __restrict__ zEb, const __hip_bfloat16* __restrict__ embB,
    const float* __restrict__ enormf, int* __restrict__ cand /*[ROWS][NC]*/) {
  __shared__ __attribute__((aligned(16))) __hip_bfloat16 Ash[64][512];    // 64 KB
  __shared__ __attribute__((aligned(16))) __hip_bfloat16 Bsh[2][32][512]; // 64 KB
  __shared__ __attribute__((aligned(16))) float EnS[K];                   // 8 KB

  const int tid  = threadIdx.x;
  const int w    = tid >> 6, lane = tid & 63;
  const int wr   = w >> 1,   wc   = w & 1;
  const int l15  = lane & 15, l4  = lane >> 4;
  const int row0 = blockIdx.x * 128;

  // ---- prologue: A slab (16 frags/wave) + enormf (2 chunks/thread) ----
#pragma unroll
  for (int i = 0; i < 16; i++) {
    int f = w*16 + i;
    int kk = f >> 3, mf = f & 7;
    gload_lds16(zEb + (((size_t)(row0 + mf*16 + l15)) << 8) + kk*32 + l4*8,
                &Ash[kk*8 + mf][0]);
  }
#pragma unroll
  for (int j = 0; j < 2; j++) {
    int p = j*256 + tid;
    gload_lds16(enormf + p*4, &EnS[p*4]);
  }
  // stage step s into slot (slot passed statically): frag (kf=w, nf=i)
  auto stageB = [&](int s, int slot) {
    const int snt = s >> 1, skh = s & 1;
#pragma unroll
    for (int i = 0; i < 8; i++) {
      gload_lds16(embB + (((size_t)(snt*128 + i*16 + l15)) << 8)
                       + skh*128 + w*32 + l4*8,
                  &Bsh[slot][w*8 + i][0]);
    }
  };
  stageB(0, 0);

  // trackers: 16 row-slots (m*4+r), top-2 as packed u32 keys (monotone f32|col)
  unsigned t0[16], t1[16];
#pragma unroll
  for (int s = 0; s < 16; s++) { t0[s] = 0xFFFFFFFFu; t1[s] = 0xFFFFFFFFu; }

  f32x4 accA[4][4], accB[4][4];
  float pen = 0.f; int pcol = 0;

  auto runphase = [&](f32x4 (&ACC)[4][4], f32x4 (&PRV)[4][4],
                      int ntbase, int pnt, bool dp) {
#pragma unroll
    for (int m = 0; m < 4; m++)
#pragma unroll
      for (int n = 0; n < 4; n++) ACC[m][n] = (f32x4){0.f, 0.f, 0.f, 0.f};
#pragma unroll
    for (int kh = 0; kh < 2; kh++) {           // 2 fat steps per nt
      const int t = ntbase*2 + kh;             // t&1 == kh (ntbase even +/- parity handled by caller)
      // all waves' prev-step reads done before overwriting the other slot
      asm volatile("s_waitcnt lgkmcnt(0)" ::: "memory");
      __builtin_amdgcn_sched_barrier(0);
      __builtin_amdgcn_s_barrier();
      if (t < 31) {
        stageB(t + 1, kh ^ 1);
        asm volatile("s_waitcnt vmcnt(8)" ::: "memory");  // own stage(t) landed
      } else {
        asm volatile("s_waitcnt vmcnt(0)" ::: "memory");
      }
      __builtin_amdgcn_sched_barrier(0);
      __builtin_amdgcn_s_barrier();            // all waves: slot kh holds step t

#pragma unroll
      for (int kk2 = 0; kk2 < 4; kk2++) {      // 4 sub-k of 32 within the step
        bf16x8 af[4], bfr[4];
#pragma unroll
        for (int m = 0; m < 4; m++)
          af[m] = *(const bf16x8*)&Ash[(kh*4 + kk2)*8 + wr*4 + m][lane*8];
#pragma unroll
        for (int n = 0; n < 4; n++)
          bfr[n] = *(const bf16x8*)&Bsh[kh][kk2*8 + wc*4 + n][lane*8];
        __builtin_amdgcn_s_setprio(1);
#pragma unroll
        for (int m = 0; m < 4; m++)
#pragma unroll
          for (int n = 0; n < 4; n++)
            ACC[m][n] = __builtin_amdgcn_mfma_f32_16x16x32_bf16(af[m], bfr[n], ACC[m][n], 0, 0, 0);
        __builtin_amdgcn_s_setprio(0);

        if (dp) {                              // deferred epilogue slice (8 vals)
          const int s2 = kh*4 + kk2;
          const int n = s2 >> 1, hf = s2 & 1;
          if (hf == 0) {
            pcol = pnt*128 + (wc*4 + n)*16 + l15;
            pen = EnS[pcol];
          }
#pragma unroll
          for (int mm = 0; mm < 2; mm++) {
            const int m = hf*2 + mm;
#pragma unroll
            for (int r = 0; r < 4; r++) {
              const float cv = fmaf(-2.f, PRV[m][n][r], pen);
              unsigned u = __float_as_uint(cv);
              unsigned key = u ^ ((unsigned)((int)u >> 31) | 0x80000000u);
              key = (key & 0xFFFFF800u) | (unsigned)pcol;
              const int s = m*4 + r;
              unsigned mx = key > t0[s] ? key : t0[s];
              t0[s] = key < t0[s] ? key : t0[s];
              t1[s] = mx < t1[s] ? mx : t1[s];
            }
          }
        }
      }
    }
  };

  for (int nt = 0; nt < 16; nt += 2) {
    runphase(accA, accB, nt,     nt - 1, nt > 0);
    runphase(accB, accA, nt + 1, nt,     true);
  }
  // tail: process accB of nt=15
#pragma unroll
  for (int s2 = 0; s2 < 8; s2++) {
    const int n = s2 >> 1, hf = s2 & 1;
    if (hf == 0) { pcol = 15*128 + (wc*4 + n)*16 + l15; pen = EnS[pcol]; }
#pragma unroll
    for (int mm = 0; mm < 2; mm++) {
      const int m = hf*2 + mm;
#pragma unroll
      for (int r = 0; r < 4; r++) {
        const float cv = fmaf(-2.f, accB[m][n][r], pen);
        unsigned u = __float_as_uint(cv);
        unsigned key = u ^ ((unsigned)((int)u >> 31) | 0x80000000u);
        key = (key & 0xFFFFF800u) | (unsigned)pcol;
        const int s = m*4 + r;
        unsigned mx = key > t0[s] ? key : t0[s];
        t0[s] = key < t0[s] ? key : t0[s];
        t1[s] = mx < t1[s] ? mx : t1[s];
      }
    }
  }

  // ---- merge 32 trackers x top-2 -> GLOBAL top-8 per row (stride 65) ----
  __syncthreads();
  unsigned* KeyM = (unsigned*)&Ash[0][0];      // [128 rows][65] = 33.3 KB
  const int tk = wc*16 + l15;
#pragma unroll
  for (int s = 0; s < 16; s++) {
    const int r = wr*64 + (s >> 2)*16 + l4*4 + (s & 3);
    KeyM[r*65 + tk*2 + 0] = t0[s];
    KeyM[r*65 + tk*2 + 1] = t1[s];
  }
  __syncthreads();
  if (tid < 128) {
    unsigned bk[8];
#pragma unroll
    for (int j = 0; j < 8; j++) bk[j] = 0xFFFFFFFFu;
    for (int e = 0; e < 64; e++) {
      unsigned v = KeyM[tid*65 + e];
      if (v < bk[7]) {
        int j = 7;
        while (j > 0 && v < bk[j-1]) { bk[j] = bk[j-1]; j--; }
        bk[j] = v;
      }
    }
    int* cr = cand + ((size_t)(row0 + tid)) * NC;
#pragma unroll
    for (int j = 0; j < 8; j++) cr[j] = (int)(bk[j] & 2047u);
  }
}

// ---------------------------------------------------------------------------
// K5 (rescore + decode fused): block per (b,h). NC=8 cands, 8 lanes/cand,
// interleaved element chunks (bank-conflict-free zsh reads).
// ---------------------------------------------------------------------------
__global__ __launch_bounds__(256) void k5_fused(
    const float* __restrict__ zE, const float* __restrict__ emb,
    const double* __restrict__ enorm, const int* __restrict__ cand,
    const float* __restrict__ wdec,
    float* __restrict__ zq, float* __restrict__ xt) {
  __shared__ __attribute__((aligned(16))) float zsh[C][256];   // 16 KB
  __shared__ __attribute__((aligned(16))) float zs[C][272];    // 17 KB
  __shared__ __attribute__((aligned(16))) float part[4][256];  // 4 KB
  __shared__ float wt[C*T];
  __shared__ int bkS[C];
  const int bh = blockIdx.x, b = bh >> 6, h = bh & 63;
  const int tid = threadIdx.x;
  const int wv = tid >> 6, lane = tid & 63;

#pragma unroll
  for (int i = 0; i < 4; i++) {
    int p = i*256 + tid;
    int c = p >> 6, cc = p & 63;
    gload_lds16(zE + ((((size_t)b*C + c)*H + h) << 8) + cc*4, &zsh[c][cc*4]);
  }
  if (tid < C*T) { int c = tid / T, t = tid % T; wt[c*T + t] = wdec[c*T + (T-1-t)]; }
  asm volatile("s_waitcnt vmcnt(0)" ::: "memory");
  __syncthreads();

  const int j = lane >> 3, q = lane & 7;
#pragma unroll
  for (int i = 0; i < 4; i++) {
    const int c = wv*4 + i;
    const size_t rid = ((size_t)b*C + c)*H + h;
    const int k = cand[rid * NC + j];
    const float* er = emb + ((size_t)k << 8);
    double a0 = 0.0, a1 = 0.0, a2 = 0.0, a3 = 0.0;
#pragma unroll
    for (int it = 0; it < 8; it++) {
      const int e0 = it*32 + q*4;
      const float4 ev = *(const float4*)(er + e0);
      const float4 zv = *(const float4*)&zsh[c][e0];
      a0 = fma((double)ev.x, (double)zv.x, a0);
      a1 = fma((double)ev.y, (double)zv.y, a1);
      a2 = fma((double)ev.z, (double)zv.z, a2);
      a3 = fma((double)ev.w, (double)zv.w, a3);
    }
    double dot = (a0 + a1) + (a2 + a3);
    dot += __shfl_xor(dot, 1, 64);
    dot += __shfl_xor(dot, 2, 64);
    dot += __shfl_xor(dot, 4, 64);
    double cv = enorm[k] - 2.0 * dot;
    int bk = k;
#pragma unroll
    for (int off = 8; off < 64; off <<= 1) {
      double ocv = __shfl_xor(cv, off, 64);
      int    okk = __shfl_xor(bk, off, 64);
      if (ocv < cv || (ocv == cv && okk < bk)) { cv = ocv; bk = okk; }
    }
    if (lane == 0) bkS[c] = bk;
  }
  __syncthreads();

  for (int i2 = tid; i2 < C*D; i2 += 256) {
    int c = i2 >> 8, dd = i2 & 255;
    float v = emb[((size_t)bkS[c] << 8) + dd];
    zs[c][dd + PAD] = v;
    zq[((((size_t)b*C + c)*H + h) << 8) + dd] = v;
  }
  { int jj = tid & 15, c = tid >> 4;
    int pos = (jj < 7) ? jj : (256 + PAD + (jj - 7));
    zs[c][pos] = 0.f; }
  __syncthreads();

  const int dg = tid & 63, cg = tid >> 6;
  float f[20];
  float oo[4] = {0.f, 0.f, 0.f, 0.f};
#pragma unroll
  for (int ci = 0; ci < 4; ci++) {
    const int c = cg*4 + ci;
#pragma unroll
    for (int kq = 0; kq < 5; kq++)
      *(float4*)&f[kq*4] = *(const float4*)&zs[c][dg*4 + kq*4];
#pragma unroll
    for (int jj = 0; jj < 4; jj++)
#pragma unroll
      for (int t = 0; t < T; t++)
        oo[jj] = fmaf(wt[c*T + t], f[jj + t], oo[jj]);
  }
  *(float4*)&part[cg][dg*4] = make_float4(oo[0], oo[1], oo[2], oo[3]);
  __syncthreads();
  float r = part[0][tid] + part[1][tid] + part[2][tid] + part[3][tid];
  xt[((size_t)bh << 8) + tid] = tanhf(r);
}

// ---------------------------------------------------------------------------
extern "C" void kernel_launch(void* const* d_in, const int* in_sizes, int n_in,
                              void* d_out, int out_size, void* d_ws, size_t ws_size,
                              hipStream_t stream) {
  const float* x     = (const float*)d_in[0];
  const float* w_enc = (const float*)d_in[1];
  const float* gamma = (const float*)d_in[2];
  const float* beta  = (const float*)d_in[3];
  const float* emb   = (const float*)d_in[4];
  const float* w_dec = (const float*)d_in[5];

  float* out = (float*)d_out;
  float* xt = out;                                    // 524288
  float* zE = out + (size_t)B*H*D;                    // 8388608 (z_e f32)
  float* zq = out + (size_t)B*H*D + (size_t)B*C*H*D;  // 8388608

  char* ws = (char*)d_ws;
  double* partial = (double*)(ws);                       // 524288 B
  double* params  = (double*)(ws + 524288);              // 512 B
  double* enorm   = (double*)(ws + 524800);              // 16384 B
  float*  enormf  = (float*) (ws + 541184);              // 8192 B
  int*    cand    = (int*)   (ws + 549376);              // 32768*8*4 = 1 MiB
  __hip_bfloat16* zEb  = (__hip_bfloat16*)(ws + 1597952);   // 16 MiB
  __hip_bfloat16* embB = (__hip_bfloat16*)(ws + 18375168);  // 1 MiB

  k0_fused<<<BH + 512, 256, 0, stream>>>(x, w_enc, partial, emb, enorm, enormf, embB);
  k2_stats_final<<<C, 256, 0, stream>>>(partial, gamma, beta, params);
  k1b_ze<<<BH, 256, 0, stream>>>(x, w_enc, params, zE, zEb);
  k4_mfma<<<ROWS/128, 256, 0, stream>>>(zEb, embB, enormf, cand);
  k5_fused<<<BH, 256, 0, stream>>>(zE, emb, enorm, cand, w_dec, zq, xt);
}

// Round 13
// 145.925 us; speedup vs baseline: 1.2017x; 1.2017x over previous
//
#include <hip/hip_runtime.h>
#include <hip/hip_bf16.h>
#include <cstddef>
#include <cstdint>

// Problem constants
#define B   32
#define C   16
#define H   64
#define D   256
#define K   2048
#define T   15
#define PAD 7
#define EPS 1e-5

#define BH      (B*H)       // 2048
#define ROWS    (B*C*H)     // 32768 VQ rows
#define N_PER_CH ((double)(B*H*D)) // 524288
#define NC  8               // candidates per row (4 per N-half)

typedef __attribute__((ext_vector_type(8))) short bf16x8;
typedef __attribute__((ext_vector_type(4))) float f32x4;

__device__ __forceinline__ void gload_lds16(const void* g, void* l) {
  __builtin_amdgcn_global_load_lds(
      (const __attribute__((address_space(1))) unsigned int*)g,
      (__attribute__((address_space(3))) unsigned int*)l, 16, 0, 0);
}

// ---------------------------------------------------------------------------
// K0 (fused): blocks [0,BH): stats-only encoder conv (f64) partial sums
//             (TRANSPOSED partial layout [c][bh] for coalesced k2 reads).
//             blocks [BH, BH+512): emb prep — enorm f64 (+f32) + bf16 cast.
// ---------------------------------------------------------------------------
__global__ __launch_bounds__(256) void k0_fused(
    const float* __restrict__ x, const float* __restrict__ w,
    double* __restrict__ partial /* [C][BH][2] */,
    const float* __restrict__ emb, double* __restrict__ enorm,
    float* __restrict__ enormf, __hip_bfloat16* __restrict__ embB) {
  __shared__ __attribute__((aligned(16))) float xs[272];
  __shared__ float wsm[C*T];
  const int bh = blockIdx.x, tid = threadIdx.x;
  if (bh >= BH) {
    const int k = (bh - BH) * 4 + (tid >> 6);
    const int lane = tid & 63;
    const float4 ev = *(const float4*)(emb + ((size_t)k << 8) + lane*4);
    __hip_bfloat16 hb[4] = {__float2bfloat16(ev.x), __float2bfloat16(ev.y),
                            __float2bfloat16(ev.z), __float2bfloat16(ev.w)};
    *(int2*)(embB + ((size_t)k << 8) + lane*4) = *(const int2*)hb;
    double s = fma((double)ev.x, (double)ev.x,
               fma((double)ev.y, (double)ev.y,
               fma((double)ev.z, (double)ev.z,
                   (double)ev.w * (double)ev.w)));
#pragma unroll
    for (int off = 1; off < 64; off <<= 1) s += __shfl_xor(s, off, 64);
    if (lane == 0) { enorm[k] = s; enormf[k] = (float)s; }
    return;
  }
  const float* xrow = x + ((size_t)bh << 8);
  if (tid < C*T) wsm[tid] = w[tid];
  xs[tid] = (tid >= 7 && tid < 263) ? xrow[tid - 7] : 0.f;
  if (tid < 16) { int i = 256 + tid; xs[i] = (i < 263) ? xrow[i - 7] : 0.f; }
  __syncthreads();
  const int c = tid >> 4, s = tid & 15;
  float xr[32];
#pragma unroll
  for (int kq = 0; kq < 8; kq++)
    *(float4*)&xr[kq*4] = *(const float4*)&xs[s*16 + kq*4];
  float wv[T];
#pragma unroll
  for (int t = 0; t < T; t++) wv[t] = wsm[c*T + t];
  double sum = 0.0, sq = 0.0;
#pragma unroll
  for (int d0 = 0; d0 < 16; d0++) {
    double z = 0.0;
#pragma unroll
    for (int t = 0; t < T; t++) z = fma((double)wv[t], (double)xr[d0 + t], z);
    sum += z; sq = fma(z, z, sq);
  }
#pragma unroll
  for (int off = 1; off < 16; off <<= 1) {
    sum += __shfl_xor(sum, off, 64);
    sq  += __shfl_xor(sq,  off, 64);
  }
  if (s == 0) {
    partial[((size_t)c*BH + bh)*2 + 0] = sum;
    partial[((size_t)c*BH + bh)*2 + 1] = sq;
  }
}

// ---------------------------------------------------------------------------
// K2: finalize BN per-channel params (deterministic tree, coalesced reads)
// ---------------------------------------------------------------------------
__global__ __launch_bounds__(256) void k2_stats_final(
    const double* __restrict__ partial, const float* __restrict__ gamma,
    const float* __restrict__ beta, double* __restrict__ params) {
  __shared__ double rs[256], rq[256];
  const int c = blockIdx.x;
  const int tid = threadIdx.x;
  double s = 0.0, q = 0.0;
  for (int i = tid; i < BH; i += 256) {
    s += partial[((size_t)c*BH + i)*2 + 0];
    q += partial[((size_t)c*BH + i)*2 + 1];
  }
  rs[tid] = s; rq[tid] = q;
  __syncthreads();
  for (int off = 128; off; off >>= 1) {
    if (tid < off) { rs[tid] += rs[tid + off]; rq[tid] += rq[tid + off]; }
    __syncthreads();
  }
  if (tid == 0) {
    double m = rs[0] / N_PER_CH;
    double v = rq[0] / N_PER_CH - m * m;
    double a = (double)gamma[c] / sqrt(v + EPS);
    double b = (double)beta[c] - a * m;
    params[c*4+0] = m; params[c*4+1] = v; params[c*4+2] = a; params[c*4+3] = b;
  }
}

// ---------------------------------------------------------------------------
// K1b: encoder conv (f64) + fused affine -> z_e f32 (output) + z_e bf16 (k4 A)
// ---------------------------------------------------------------------------
__global__ __launch_bounds__(256) void k1b_ze(
    const float* __restrict__ x, const float* __restrict__ w,
    const double* __restrict__ params, float* __restrict__ zE,
    __hip_bfloat16* __restrict__ zEb) {
  __shared__ __attribute__((aligned(16))) float xs[272];
  __shared__ float wsm[C*T];
  const int bh = blockIdx.x, tid = threadIdx.x;
  const int b = bh >> 6, h = bh & 63;
  const float* xrow = x + ((size_t)bh << 8);
  if (tid < C*T) wsm[tid] = w[tid];
  xs[tid] = (tid >= 7 && tid < 263) ? xrow[tid - 7] : 0.f;
  if (tid < 16) { int i = 256 + tid; xs[i] = (i < 263) ? xrow[i - 7] : 0.f; }
  __syncthreads();
  const int c = tid >> 4, s = tid & 15;
  float xr[32];
#pragma unroll
  for (int kq = 0; kq < 8; kq++)
    *(float4*)&xr[kq*4] = *(const float4*)&xs[s*16 + kq*4];
  float wv[T];
#pragma unroll
  for (int t = 0; t < T; t++) wv[t] = wsm[c*T + t];
  const double a = params[c*4+2], bb = params[c*4+3];
  float zf[16];
  __hip_bfloat16 zb[16];
#pragma unroll
  for (int d0 = 0; d0 < 16; d0++) {
    double z = 0.0;
#pragma unroll
    for (int t = 0; t < T; t++) z = fma((double)wv[t], (double)xr[d0 + t], z);
    double ze = fma(a, z, bb);
    zf[d0] = (float)ze;
    zb[d0] = __float2bfloat16(zf[d0]);
  }
  const size_t rbase = ((((size_t)b*C + c)*H + h) << 8) + s*16;
#pragma unroll
  for (int kq = 0; kq < 4; kq++)
    *(float4*)(zE + rbase + kq*4) = *(const float4*)&zf[kq*4];
  *(int4*)(zEb + rbase)     = *(const int4*)&zb[0];
  *(int4*)(zEb + rbase + 8) = *(const int4*)&zb[8];
}

// ---------------------------------------------------------------------------
// K4: round-4's measured-best structure (83.5 us) + exact-count fix:
// enormf prefetched to REGISTERS at kk==0 (used next phase), so the main
// loop has zero stray VMEM; per-kk counted waits: kk==1 -> vmcnt(6)
// (queue [st(t)2, en4, st(t+1)2] -> drains exactly st(t)), else vmcnt(2).
// A slab (128x256, frag-order, 64 KB) resident; B 2-slot ring (16 KB)
// collectively staged; acc double-buffer with spread tracker epilogue.
// Merge -> top-4 per N-half (NC=8).
// ---------------------------------------------------------------------------
__global__ __launch_bounds__(256, 2) void k4_mfma(
    const __hip_bfloat16* __restrict__ zEb, const __hip_bfloat16* __restrict__ embB,
    const float* __restrict__ enormf, int* __restrict__ cand /*[ROWS][NC]*/) {
  __shared__ __attribute__((aligned(16))) __hip_bfloat16 Ash[64][512];   // 64 KB
  __shared__ __attribute__((aligned(16))) __hip_bfloat16 Bsh[2][8][512]; // 16 KB

  const int tid  = threadIdx.x;
  const int w    = tid >> 6, lane = tid & 63;
  const int wr   = w >> 1,   wc   = w & 1;
  const int l15  = lane & 15, l4  = lane >> 4;
  const int mblk = blockIdx.x >> 1, nhalf = blockIdx.x & 1;
  const int row0 = mblk * 128;
  const int n0   = nhalf * 1024;

  // ---- prologue: A slab (64 frags) + B step 0 ----
#pragma unroll
  for (int i = 0; i < 16; i++) {
    int f = w*16 + i;
    int kk = f >> 3, mf = f & 7;
    gload_lds16(zEb + (((size_t)(row0 + mf*16 + l15)) << 8) + kk*32 + l4*8,
                &Ash[kk*8 + mf][0]);
  }
  auto stageB = [&](int t) {
    const int slot = t & 1, nt = t >> 3, kk = t & 7;
#pragma unroll
    for (int j = 0; j < 2; j++) {
      int nf = w*2 + j;
      gload_lds16(embB + (((size_t)(n0 + nt*128 + nf*16 + l15)) << 8) + kk*32 + l4*8,
                  &Bsh[slot][nf][0]);
    }
  };
  stageB(0);
  asm volatile("s_waitcnt vmcnt(0) lgkmcnt(0)" ::: "memory");
  __builtin_amdgcn_sched_barrier(0);
  __builtin_amdgcn_s_barrier();

  // trackers: 16 row-slots (m*4+r), top-2 as packed u32 keys (monotone f32|col)
  unsigned t0[16], t1[16];
#pragma unroll
  for (int s = 0; s < 16; s++) { t0[s] = 0xFFFFFFFFu; t1[s] = 0xFFFFFFFFu; }

  f32x4 accA[4][4], accB[4][4];
  float enC0 = 0.f, enC1 = 0.f, enC2 = 0.f, enC3 = 0.f;   // current phase en
  float enP0 = 0.f, enP1 = 0.f, enP2 = 0.f, enP3 = 0.f;   // previous phase en

  auto runphase = [&](f32x4 (&ACC)[4][4], f32x4 (&PRV)[4][4],
                      int ntbase, int pnt, bool dp) {
#pragma unroll
    for (int m = 0; m < 4; m++)
#pragma unroll
      for (int n = 0; n < 4; n++) ACC[m][n] = (f32x4){0.f, 0.f, 0.f, 0.f};

#pragma unroll
    for (int kk = 0; kk < 8; kk++) {
      const int t = ntbase*8 + kk;
      if (t) __builtin_amdgcn_s_barrier();       // barrier_A: prev reads consumed
      if (t < 63) {
        stageB(t + 1);
        if (kk == 1) asm volatile("s_waitcnt vmcnt(6)" ::: "memory");
        else         asm volatile("s_waitcnt vmcnt(2)" ::: "memory");
      } else {
        asm volatile("s_waitcnt vmcnt(0)" ::: "memory");
      }
      __builtin_amdgcn_sched_barrier(0);
      __builtin_amdgcn_s_barrier();              // barrier_B: stage(t) visible

      if (kk == 0) {                             // rotate en regs; prefetch this
        enP0 = enC0; enP1 = enC1; enP2 = enC2; enP3 = enC3;  // phase's en (used
        enC0 = enormf[n0 + ntbase*128 + (wc*4 + 0)*16 + l15];// next phase)
        enC1 = enormf[n0 + ntbase*128 + (wc*4 + 1)*16 + l15];
        enC2 = enormf[n0 + ntbase*128 + (wc*4 + 2)*16 + l15];
        enC3 = enormf[n0 + ntbase*128 + (wc*4 + 3)*16 + l15];
      }

      bf16x8 af[4], bfr[4];
#pragma unroll
      for (int m = 0; m < 4; m++)
        af[m] = *(const bf16x8*)&Ash[kk*8 + wr*4 + m][lane*8];
#pragma unroll
      for (int n = 0; n < 4; n++)
        bfr[n] = *(const bf16x8*)&Bsh[t & 1][wc*4 + n][lane*8];
#pragma unroll
      for (int m = 0; m < 4; m++)
#pragma unroll
        for (int n = 0; n < 4; n++)
          acc_dummy: ;
#pragma unroll
      for (int m = 0; m < 4; m++)
#pragma unroll
        for (int n = 0; n < 4; n++)
          ACC[m][n] = __builtin_amdgcn_mfma_f32_16x16x32_bf16(af[m], bfr[n], ACC[m][n], 0, 0, 0);

      if (dp) {                                  // deferred epilogue slice (8 vals)
        const int n = kk >> 1, hf = kk & 1;
        const float pen = (n == 0) ? enP0 : (n == 1) ? enP1 : (n == 2) ? enP2 : enP3;
        const int pcol = n0 + pnt*128 + (wc*4 + n)*16 + l15;
#pragma unroll
        for (int mm = 0; mm < 2; mm++) {
          const int m = hf*2 + mm;
#pragma unroll
          for (int r = 0; r < 4; r++) {
            const float cv = fmaf(-2.f, PRV[m][n][r], pen);
            unsigned u = __float_as_uint(cv);
            unsigned key = u ^ ((unsigned)((int)u >> 31) | 0x80000000u);
            key = (key & 0xFFFFF800u) | (unsigned)pcol;
            const int s = m*4 + r;
            unsigned mx = key > t0[s] ? key : t0[s];
            t0[s] = key < t0[s] ? key : t0[s];
            t1[s] = mx < t1[s] ? mx : t1[s];
          }
        }
      }
    }
  };

  for (int nt = 0; nt < 8; nt += 2) {
    runphase(accA, accB, nt,     nt - 1, nt > 0);
    runphase(accB, accA, nt + 1, nt,     true);
  }
  // tail: process accB of nt=7 (en of nt=7 is in enC)
#pragma unroll
  for (int kk = 0; kk < 8; kk++) {
    const int n = kk >> 1, hf = kk & 1;
    const float pen = (n == 0) ? enC0 : (n == 1) ? enC1 : (n == 2) ? enC2 : enC3;
    const int pcol = n0 + 7*128 + (wc*4 + n)*16 + l15;
#pragma unroll
    for (int mm = 0; mm < 2; mm++) {
      const int m = hf*2 + mm;
#pragma unroll
      for (int r = 0; r < 4; r++) {
        const float cv = fmaf(-2.f, accB[m][n][r], pen);
        unsigned u = __float_as_uint(cv);
        unsigned key = u ^ ((unsigned)((int)u >> 31) | 0x80000000u);
        key = (key & 0xFFFFF800u) | (unsigned)pcol;
        const int s = m*4 + r;
        unsigned mx = key > t0[s] ? key : t0[s];
        t0[s] = key < t0[s] ? key : t0[s];
        t1[s] = mx < t1[s] ? mx : t1[s];
      }
    }
  }

  // ---- merge 32 trackers x top-2 -> top-4 per row (stride 65: no conflicts) ----
  __syncthreads();
  unsigned* KeyM = (unsigned*)&Ash[0][0];      // [128 rows][65] = 33.3 KB
  const int tk = wc*16 + l15;
#pragma unroll
  for (int s = 0; s < 16; s++) {
    const int r = wr*64 + (s >> 2)*16 + l4*4 + (s & 3);
    KeyM[r*65 + tk*2 + 0] = t0[s];
    KeyM[r*65 + tk*2 + 1] = t1[s];
  }
  __syncthreads();
  if (tid < 128) {
    unsigned bk[4];
#pragma unroll
    for (int j = 0; j < 4; j++) bk[j] = 0xFFFFFFFFu;
    for (int e = 0; e < 64; e++) {
      unsigned v = KeyM[tid*65 + e];
      if (v < bk[3]) {
        int j = 3;
        while (j > 0 && v < bk[j-1]) { bk[j] = bk[j-1]; j--; }
        bk[j] = v;
      }
    }
    int* cr = cand + ((size_t)(row0 + tid)) * NC + nhalf*4;
#pragma unroll
    for (int j = 0; j < 4; j++) cr[j] = (int)(bk[j] & 2047u);
  }
}

// ---------------------------------------------------------------------------
// K5 (rescore + decode fused): block per (b,h). NC=8 cands, 8 lanes/cand,
// interleaved element chunks (bank-conflict-free zsh reads).
// ---------------------------------------------------------------------------
__global__ __launch_bounds__(256) void k5_fused(
    const float* __restrict__ zE, const float* __restrict__ emb,
    const double* __restrict__ enorm, const int* __restrict__ cand,
    const float* __restrict__ wdec,
    float* __restrict__ zq, float* __restrict__ xt) {
  __shared__ __attribute__((aligned(16))) float zsh[C][256];   // 16 KB
  __shared__ __attribute__((aligned(16))) float zs[C][272];    // 17 KB
  __shared__ __attribute__((aligned(16))) float part[4][256];  // 4 KB
  __shared__ float wt[C*T];
  __shared__ int bkS[C];
  const int bh = blockIdx.x, b = bh >> 6, h = bh & 63;
  const int tid = threadIdx.x;
  const int wv = tid >> 6, lane = tid & 63;

#pragma unroll
  for (int i = 0; i < 4; i++) {
    int p = i*256 + tid;
    int c = p >> 6, cc = p & 63;
    gload_lds16(zE + ((((size_t)b*C + c)*H + h) << 8) + cc*4, &zsh[c][cc*4]);
  }
  if (tid < C*T) { int c = tid / T, t = tid % T; wt[c*T + t] = wdec[c*T + (T-1-t)]; }
  asm volatile("s_waitcnt vmcnt(0)" ::: "memory");
  __syncthreads();

  const int j = lane >> 3, q = lane & 7;
#pragma unroll
  for (int i = 0; i < 4; i++) {
    const int c = wv*4 + i;
    const size_t rid = ((size_t)b*C + c)*H + h;
    const int k = cand[rid * NC + j];
    const float* er = emb + ((size_t)k << 8);
    double a0 = 0.0, a1 = 0.0, a2 = 0.0, a3 = 0.0;
#pragma unroll
    for (int it = 0; it < 8; it++) {
      const int e0 = it*32 + q*4;
      const float4 ev = *(const float4*)(er + e0);
      const float4 zv = *(const float4*)&zsh[c][e0];
      a0 = fma((double)ev.x, (double)zv.x, a0);
      a1 = fma((double)ev.y, (double)zv.y, a1);
      a2 = fma((double)ev.z, (double)zv.z, a2);
      a3 = fma((double)ev.w, (double)zv.w, a3);
    }
    double dot = (a0 + a1) + (a2 + a3);
    dot += __shfl_xor(dot, 1, 64);
    dot += __shfl_xor(dot, 2, 64);
    dot += __shfl_xor(dot, 4, 64);
    double cv = enorm[k] - 2.0 * dot;
    int bk = k;
#pragma unroll
    for (int off = 8; off < 64; off <<= 1) {
      double ocv = __shfl_xor(cv, off, 64);
      int    okk = __shfl_xor(bk, off, 64);
      if (ocv < cv || (ocv == cv && okk < bk)) { cv = ocv; bk = okk; }
    }
    if (lane == 0) bkS[c] = bk;
  }
  __syncthreads();

  for (int i2 = tid; i2 < C*D; i2 += 256) {
    int c = i2 >> 8, dd = i2 & 255;
    float v = emb[((size_t)bkS[c] << 8) + dd];
    zs[c][dd + PAD] = v;
    zq[((((size_t)b*C + c)*H + h) << 8) + dd] = v;
  }
  { int jj = tid & 15, c = tid >> 4;
    int pos = (jj < 7) ? jj : (256 + PAD + (jj - 7));
    zs[c][pos] = 0.f; }
  __syncthreads();

  const int dg = tid & 63, cg = tid >> 6;
  float f[20];
  float oo[4] = {0.f, 0.f, 0.f, 0.f};
#pragma unroll
  for (int ci = 0; ci < 4; ci++) {
    const int c = cg*4 + ci;
#pragma unroll
    for (int kq = 0; kq < 5; kq++)
      *(float4*)&f[kq*4] = *(const float4*)&zs[c][dg*4 + kq*4];
#pragma unroll
    for (int jj = 0; jj < 4; jj++)
#pragma unroll
      for (int t = 0; t < T; t++)
        oo[jj] = fmaf(wt[c*T + t], f[jj + t], oo[jj]);
  }
  *(float4*)&part[cg][dg*4] = make_float4(oo[0], oo[1], oo[2], oo[3]);
  __syncthreads();
  float r = part[0][tid] + part[1][tid] + part[2][tid] + part[3][tid];
  xt[((size_t)bh << 8) + tid] = tanhf(r);
}

// ---------------------------------------------------------------------------
extern "C" void kernel_launch(void* const* d_in, const int* in_sizes, int n_in,
                              void* d_out, int out_size, void* d_ws, size_t ws_size,
                              hipStream_t stream) {
  const float* x     = (const float*)d_in[0];
  const float* w_enc = (const float*)d_in[1];
  const float* gamma = (const float*)d_in[2];
  const float* beta  = (const float*)d_in[3];
  const float* emb   = (const float*)d_in[4];
  const float* w_dec = (const float*)d_in[5];

  float* out = (float*)d_out;
  float* xt = out;                                    // 524288
  float* zE = out + (size_t)B*H*D;                    // 8388608 (z_e f32)
  float* zq = out + (size_t)B*H*D + (size_t)B*C*H*D;  // 8388608

  char* ws = (char*)d_ws;
  double* partial = (double*)(ws);                       // 524288 B
  double* params  = (double*)(ws + 524288);              // 512 B
  double* enorm   = (double*)(ws + 524800);              // 16384 B
  float*  enormf  = (float*) (ws + 541184);              // 8192 B
  int*    cand    = (int*)   (ws + 549376);              // 32768*8*4 = 1 MiB
  __hip_bfloat16* zEb  = (__hip_bfloat16*)(ws + 1597952);   // 16 MiB
  __hip_bfloat16* embB = (__hip_bfloat16*)(ws + 18375168);  // 1 MiB

  k0_fused<<<BH + 512, 256, 0, stream>>>(x, w_enc, partial, emb, enorm, enormf, embB);
  k2_stats_final<<<C, 256, 0, stream>>>(partial, gamma, beta, params);
  k1b_ze<<<BH, 256, 0, stream>>>(x, w_enc, params, zE, zEb);
  k4_mfma<<<512, 256, 0, stream>>>(zEb, embB, enormf, cand);
  k5_fused<<<BH, 256, 0, stream>>>(zE, emb, enorm, cand, w_dec, zq, xt);
}